// Round 3
// baseline (411.868 us; speedup 1.0000x reference)
//
#include <hip/hip_runtime.h>
#include <hip/hip_bf16.h>
#include <stdint.h>

typedef __bf16 bf16;
typedef __bf16 bf16x8 __attribute__((ext_vector_type(8)));
typedef float  f32x4  __attribute__((ext_vector_type(4)));

#define D_MODEL 1024
#define N_HEADS 16
#define HEAD_DIM 64
#define SEQ 2048
#define BATCH 2
#define LOG2E 1.4426950408889634f
#define NEG_SENT -3.0e4f   // finite "-inf": exp2f(NEG_SENT - mn) == 0; never NaNs

__device__ __forceinline__ bf16x8 ld8(const bf16* p) { return *(const bf16x8*)p; }

// ---------------- fp32 -> bf16 elementwise convert ----------------
__global__ void cvt_f32_bf16(const float* __restrict__ in, bf16* __restrict__ out, int n) {
  int i = (blockIdx.x * blockDim.x + threadIdx.x) * 4;
  if (i < n) {
    float4 v = *(const float4*)&in[i];
    bf16 o[4] = {(bf16)v.x, (bf16)v.y, (bf16)v.z, (bf16)v.w};
    *(uint2*)&out[i] = *(uint2*)o;
  }
}

// ---------------- weight transpose+convert: fp32 (R x C) -> bf16 (C x R) ----------------
__global__ void transpose_cvt(const float* __restrict__ in, bf16* __restrict__ out,
                              int R, int C) {
  __shared__ float tile[32][33];
  int c0 = blockIdx.x * 32, r0 = blockIdx.y * 32;
  int tx = threadIdx.x;
  for (int i = threadIdx.y; i < 32; i += 8)
    tile[i][tx] = in[(size_t)(r0 + i) * C + c0 + tx];
  __syncthreads();
  for (int i = threadIdx.y; i < 32; i += 8)
    out[(size_t)(c0 + i) * R + r0 + tx] = (bf16)tile[tx][i];
}

// ---------------- GEMM: C[M x N] = A[M x 1024] * Bt[N x 1024]^T + bias ----------------
// mode 0: scatter into Q (bh,t,d), K (bh,t,d), Vt (bh,d,t)   [bf16]
// mode 1: plain row-major fp32 store to outf (ld = N)
__global__ __launch_bounds__(256)
void gemm_bt(const bf16* __restrict__ A, const bf16* __restrict__ Bt,
             const float* __restrict__ bias, float* __restrict__ outf,
             bf16* __restrict__ Qp, bf16* __restrict__ Kp, bf16* __restrict__ Vtp,
             int N, int mode) {
  // pad LDS row stride to 40 elems (80B) to break bank-conflict strides
  __shared__ __align__(16) bf16 shA[128 * 40];
  __shared__ __align__(16) bf16 shB[128 * 40];
  const int tid  = threadIdx.x;
  const int bm0  = blockIdx.y * 128, bn0 = blockIdx.x * 128;
  const int wave = tid >> 6, lane = tid & 63;
  const int quad = lane >> 4, l16 = lane & 15;
  const int wm = (wave >> 1) * 64, wn = (wave & 1) * 64;

  f32x4 acc[4][4];
  #pragma unroll
  for (int i = 0; i < 4; i++)
    #pragma unroll
    for (int j = 0; j < 4; j++)
      acc[i][j] = (f32x4){0.f, 0.f, 0.f, 0.f};

  for (int k0 = 0; k0 < 1024; k0 += 32) {
    #pragma unroll
    for (int s = 0; s < 2; s++) {
      int c = tid + s * 256;           // 0..511 chunk id, 16B each
      int row = c >> 2;                // 0..127
      int kc  = (c & 3) << 3;          // 0,8,16,24
      *(uint4*)&shA[row * 40 + kc] =
          *(const uint4*)&A[(size_t)(bm0 + row) * 1024 + k0 + kc];
      *(uint4*)&shB[row * 40 + kc] =
          *(const uint4*)&Bt[(size_t)(bn0 + row) * 1024 + k0 + kc];
    }
    __syncthreads();
    bf16x8 af[4], bg[4];
    #pragma unroll
    for (int i = 0; i < 4; i++)
      af[i] = ld8(&shA[(wm + i * 16 + l16) * 40 + quad * 8]);
    #pragma unroll
    for (int j = 0; j < 4; j++)
      bg[j] = ld8(&shB[(wn + j * 16 + l16) * 40 + quad * 8]);
    #pragma unroll
    for (int i = 0; i < 4; i++)
      #pragma unroll
      for (int j = 0; j < 4; j++)
        acc[i][j] = __builtin_amdgcn_mfma_f32_16x16x32_bf16(af[i], bg[j], acc[i][j], 0, 0, 0);
    __syncthreads();
  }

  // epilogue; C/D layout: col = lane&15, row = quad*4 + reg   [verified m89/m91]
  #pragma unroll
  for (int i = 0; i < 4; i++) {
    #pragma unroll
    for (int j = 0; j < 4; j++) {
      int gn = bn0 + wn + j * 16 + l16;
      float bv = bias[gn];
      #pragma unroll
      for (int r = 0; r < 4; r++) {
        int gm = bm0 + wm + i * 16 + quad * 4 + r;
        float v = acc[i][j][r] + bv;
        if (mode == 1) {
          outf[(size_t)gm * N + gn] = v;
        } else {
          int which = gn >> 10, rem = gn & 1023;
          int h = rem >> 6, d = rem & 63;
          int b = gm >> 11, t = gm & 2047;
          int bh = b * N_HEADS + h;
          if (which == 0)      Qp[((size_t)bh * SEQ + t) * 64 + d]  = (bf16)v;
          else if (which == 1) Kp[((size_t)bh * SEQ + t) * 64 + d]  = (bf16)v;
          else                 Vtp[((size_t)bh * 64 + d) * SEQ + t] = (bf16)v;
        }
      }
    }
  }
}

// ---------------- flash attention (causal), one wave = 16 q rows ----------------
__global__ __launch_bounds__(256)
void attn_k(const bf16* __restrict__ Qp, const bf16* __restrict__ Kp,
            const bf16* __restrict__ Vtp, bf16* __restrict__ Obuf) {
  __shared__ __align__(16) bf16 shP[4][16 * 40];   // per-wave P round-trip
  const int tid  = threadIdx.x;
  const int wave = tid >> 6, lane = tid & 63;
  const int quad = lane >> 4, l16 = lane & 15;
  const int bh = blockIdx.y;
  const int q0 = blockIdx.x * 64 + wave * 16;      // 16 q rows per wave

  const bf16* Qbh = Qp  + (size_t)bh * SEQ * 64;
  const bf16* Kbh = Kp  + (size_t)bh * SEQ * 64;
  const bf16* Vbh = Vtp + (size_t)bh * 64 * SEQ;   // (d, t)

  // A-operand layout: A[m=lane&15][k=quad*8+j]   [verified m120]
  bf16x8 aQ0 = ld8(&Qbh[(size_t)(q0 + l16) * 64 + quad * 8]);
  bf16x8 aQ1 = ld8(&Qbh[(size_t)(q0 + l16) * 64 + 32 + quad * 8]);

  f32x4 o[4];
  #pragma unroll
  for (int j = 0; j < 4; j++) o[j] = (f32x4){0.f, 0.f, 0.f, 0.f};
  float mrow[4], lrow[4];
  #pragma unroll
  for (int r = 0; r < 4; r++) { mrow[r] = NEG_SENT; lrow[r] = 0.f; }

  const float SC = 0.125f * LOG2E;   // 1/sqrt(64) folded with log2(e) for exp2
  const int L = (q0 + 15) >> 5;      // last 32-key tile index (only one needing a mask)
  bf16* P = shP[wave];

  for (int kt = 0; kt <= L; kt++) {
    const int kbase = kt * 32;
    f32x4 s[2];
    s[0] = (f32x4){0.f, 0.f, 0.f, 0.f};
    s[1] = (f32x4){0.f, 0.f, 0.f, 0.f};
    #pragma unroll
    for (int c = 0; c < 2; c++) {
      bf16x8 bK0 = ld8(&Kbh[(size_t)(kbase + c * 16 + l16) * 64 + quad * 8]);
      bf16x8 bK1 = ld8(&Kbh[(size_t)(kbase + c * 16 + l16) * 64 + 32 + quad * 8]);
      s[c] = __builtin_amdgcn_mfma_f32_16x16x32_bf16(aQ0, bK0, s[c], 0, 0, 0);
      s[c] = __builtin_amdgcn_mfma_f32_16x16x32_bf16(aQ1, bK1, s[c], 0, 0, 0);
    }
    // scale + causal mask (only last tile can straddle the diagonal).
    #pragma unroll
    for (int c = 0; c < 2; c++)
      #pragma unroll
      for (int r = 0; r < 4; r++) {
        float v = s[c][r] * SC;
        if (kt == L) {
          int key = kbase + c * 16 + l16;
          int row = q0 + quad * 4 + r;
          if (key > row) v = NEG_SENT;
        }
        s[c][r] = v;
      }
    // online softmax; a row's 16 cols live in lanes quad*16+0..15
    #pragma unroll
    for (int r = 0; r < 4; r++) {
      float mx = fmaxf(s[0][r], s[1][r]);
      #pragma unroll
      for (int off = 1; off < 16; off <<= 1)
        mx = fmaxf(mx, __shfl_xor(mx, off, 64));
      float mn = fmaxf(mrow[r], mx);
      float alpha = exp2f(mrow[r] - mn);       // finite - finite: never NaN
      float p0 = exp2f(s[0][r] - mn);
      float p1 = exp2f(s[1][r] - mn);
      s[0][r] = p0; s[1][r] = p1;
      float rs = p0 + p1;
      #pragma unroll
      for (int off = 1; off < 16; off <<= 1)
        rs += __shfl_xor(rs, off, 64);
      lrow[r] = lrow[r] * alpha + rs;
      mrow[r] = mn;
      #pragma unroll
      for (int j = 0; j < 4; j++) o[j][r] *= alpha;
    }
    // P: C-layout -> LDS -> A-layout (in-wave, no barrier needed)
    #pragma unroll
    for (int c = 0; c < 2; c++)
      #pragma unroll
      for (int r = 0; r < 4; r++)
        P[(quad * 4 + r) * 40 + c * 16 + l16] = (bf16)s[c][r];
    asm volatile("s_waitcnt lgkmcnt(0)" ::: "memory");
    bf16x8 aP = ld8(&P[l16 * 40 + quad * 8]);   // all 32 keys in one A-frag
    #pragma unroll
    for (int j = 0; j < 4; j++) {
      bf16x8 bV = ld8(&Vbh[(size_t)(j * 16 + l16) * SEQ + kbase + quad * 8]);
      o[j] = __builtin_amdgcn_mfma_f32_16x16x32_bf16(aP, bV, o[j], 0, 0, 0);
    }
  }

  // finalize: divide by l, store to (b, t, h*64+d)
  const int b = bh >> 4, h = bh & 15;
  #pragma unroll
  for (int r = 0; r < 4; r++) {
    float inv = 1.0f / lrow[r];
    int t = q0 + quad * 4 + r;
    size_t rowo = ((size_t)(b * SEQ + t)) * D_MODEL + h * 64;
    #pragma unroll
    for (int j = 0; j < 4; j++)
      Obuf[rowo + j * 16 + l16] = (bf16)(o[j][r] * inv);
  }
}

extern "C" void kernel_launch(void* const* d_in, const int* in_sizes, int n_in,
                              void* d_out, int out_size, void* d_ws, size_t ws_size,
                              hipStream_t stream) {
  const float* x    = (const float*)d_in[0];   // (2,2048,1024) fp32
  const float* Wqkv = (const float*)d_in[1];   // (1024,3072)  fp32
  const float* bqkv = (const float*)d_in[2];   // (3072,)      fp32
  const float* Wout = (const float*)d_in[3];   // (1024,1024)  fp32
  const float* bout = (const float*)d_in[4];   // (1024,)      fp32
  float* out = (float*)d_out;                  // (2,2048,1024) fp32

  char* ws = (char*)d_ws;
  // x_bf16 (8 MB) is reused as Obuf after gemm0 has consumed x (same-stream serialization)
  bf16* x16    = (bf16*)(ws);                     //  8 MB: (4096,1024) bf16; later Obuf
  bf16* Wqkv_t = (bf16*)(ws + 8388608);           //  6 MB: (3072,1024) bf16
  bf16* Wout_t = (bf16*)(ws + 14680064);          //  2 MB: (1024,1024) bf16
  bf16* Qp     = (bf16*)(ws + 16777216);          //  8 MB: (32,2048,64)
  bf16* Kp     = (bf16*)(ws + 25165824);          //  8 MB: (32,2048,64)
  bf16* Vtp    = (bf16*)(ws + 33554432);          //  8 MB: (32,64,2048)  -> total 40 MB
  bf16* Obuf   = x16;

  cvt_f32_bf16<<<(4096 * 1024 / 4 + 255) / 256, 256, 0, stream>>>(x, x16, 4096 * 1024);
  transpose_cvt<<<dim3(3072 / 32, 1024 / 32), dim3(32, 8), 0, stream>>>(Wqkv, Wqkv_t, 1024, 3072);
  transpose_cvt<<<dim3(1024 / 32, 1024 / 32), dim3(32, 8), 0, stream>>>(Wout, Wout_t, 1024, 1024);

  gemm_bt<<<dim3(3072 / 128, 4096 / 128), 256, 0, stream>>>(
      x16, Wqkv_t, bqkv, nullptr, Qp, Kp, Vtp, 3072, 0);

  attn_k<<<dim3(SEQ / 64, BATCH * N_HEADS), 256, 0, stream>>>(Qp, Kp, Vtp, Obuf);

  gemm_bt<<<dim3(1024 / 128, 4096 / 128), 256, 0, stream>>>(
      Obuf, Wout_t, bout, out, nullptr, nullptr, nullptr, 1024, 1);
}

// Round 4
// 323.637 us; speedup vs baseline: 1.2726x; 1.2726x over previous
//
#include <hip/hip_runtime.h>
#include <hip/hip_bf16.h>
#include <stdint.h>

typedef __bf16 bf16;
typedef __bf16 bf16x8 __attribute__((ext_vector_type(8)));
typedef float  f32x4  __attribute__((ext_vector_type(4)));

#define D_MODEL 1024
#define N_HEADS 16
#define HEAD_DIM 64
#define SEQ 2048
#define BATCH 2
#define LOG2E 1.4426950408889634f
#define NEG_SENT -3.0e4f   // finite "-inf": exp2f(NEG_SENT - mn) == 0; never NaNs

__device__ __forceinline__ bf16x8 ld8(const bf16* p) { return *(const bf16x8*)p; }

// ---------------- fp32 -> bf16 elementwise convert ----------------
__global__ void cvt_f32_bf16(const float* __restrict__ in, bf16* __restrict__ out, int n) {
  int i = (blockIdx.x * blockDim.x + threadIdx.x) * 4;
  if (i < n) {
    float4 v = *(const float4*)&in[i];
    bf16 o[4] = {(bf16)v.x, (bf16)v.y, (bf16)v.z, (bf16)v.w};
    *(uint2*)&out[i] = *(uint2*)o;
  }
}

// ---------------- weight transpose+convert: fp32 (R x C) -> bf16 (C x R) ----------------
__global__ void transpose_cvt(const float* __restrict__ in, bf16* __restrict__ out,
                              int R, int C) {
  __shared__ float tile[32][33];
  int c0 = blockIdx.x * 32, r0 = blockIdx.y * 32;
  int tx = threadIdx.x;
  for (int i = threadIdx.y; i < 32; i += 8)
    tile[i][tx] = in[(size_t)(r0 + i) * C + c0 + tx];
  __syncthreads();
  for (int i = threadIdx.y; i < 32; i += 8)
    out[(size_t)(c0 + i) * R + r0 + tx] = (bf16)tile[tx][i];
}

// ---------------- GEMM: C[M x N] = A[M x 1024] * Bt[N x 1024]^T + bias ----------------
// mode 0: scatter into Q (bh,t,d), K (bh,t,d), Vt (bh,d,t)   [bf16]
// mode 1: plain row-major fp32 store to outf (ld = N)
__global__ __launch_bounds__(256)
void gemm_bt(const bf16* __restrict__ A, const bf16* __restrict__ Bt,
             const float* __restrict__ bias, float* __restrict__ outf,
             bf16* __restrict__ Qp, bf16* __restrict__ Kp, bf16* __restrict__ Vtp,
             int N, int mode) {
  __shared__ __align__(16) bf16 shA[128 * 40];
  __shared__ __align__(16) bf16 shB[128 * 40];
  const int tid  = threadIdx.x;
  const int bm0  = blockIdx.y * 128, bn0 = blockIdx.x * 128;
  const int wave = tid >> 6, lane = tid & 63;
  const int quad = lane >> 4, l16 = lane & 15;
  const int wm = (wave >> 1) * 64, wn = (wave & 1) * 64;

  f32x4 acc[4][4];
  #pragma unroll
  for (int i = 0; i < 4; i++)
    #pragma unroll
    for (int j = 0; j < 4; j++)
      acc[i][j] = (f32x4){0.f, 0.f, 0.f, 0.f};

  for (int k0 = 0; k0 < 1024; k0 += 32) {
    #pragma unroll
    for (int s = 0; s < 2; s++) {
      int c = tid + s * 256;
      int row = c >> 2;
      int kc  = (c & 3) << 3;
      *(uint4*)&shA[row * 40 + kc] =
          *(const uint4*)&A[(size_t)(bm0 + row) * 1024 + k0 + kc];
      *(uint4*)&shB[row * 40 + kc] =
          *(const uint4*)&Bt[(size_t)(bn0 + row) * 1024 + k0 + kc];
    }
    __syncthreads();
    bf16x8 af[4], bg[4];
    #pragma unroll
    for (int i = 0; i < 4; i++)
      af[i] = ld8(&shA[(wm + i * 16 + l16) * 40 + quad * 8]);
    #pragma unroll
    for (int j = 0; j < 4; j++)
      bg[j] = ld8(&shB[(wn + j * 16 + l16) * 40 + quad * 8]);
    #pragma unroll
    for (int i = 0; i < 4; i++)
      #pragma unroll
      for (int j = 0; j < 4; j++)
        acc[i][j] = __builtin_amdgcn_mfma_f32_16x16x32_bf16(af[i], bg[j], acc[i][j], 0, 0, 0);
    __syncthreads();
  }

  // epilogue; C/D layout: col = lane&15, row = quad*4 + reg   [verified m89/m91]
  #pragma unroll
  for (int i = 0; i < 4; i++) {
    #pragma unroll
    for (int j = 0; j < 4; j++) {
      int gn = bn0 + wn + j * 16 + l16;
      float bv = bias[gn];
      #pragma unroll
      for (int r = 0; r < 4; r++) {
        int gm = bm0 + wm + i * 16 + quad * 4 + r;
        float v = acc[i][j][r] + bv;
        if (mode == 1) {
          outf[(size_t)gm * N + gn] = v;
        } else {
          int which = gn >> 10, rem = gn & 1023;
          int h = rem >> 6, d = rem & 63;
          int b = gm >> 11, t = gm & 2047;
          int bh = b * N_HEADS + h;
          if (which == 0)      Qp[((size_t)bh * SEQ + t) * 64 + d]  = (bf16)v;
          else if (which == 1) Kp[((size_t)bh * SEQ + t) * 64 + d]  = (bf16)v;
          else                 Vtp[((size_t)bh * 64 + d) * SEQ + t] = (bf16)v;
        }
      }
    }
  }
}

// ---------------- flash attention (causal) v2 ----------------
// Block = 4 waves = 64 q rows; K/V staged in LDS per 64-key tile, shared by all waves.
// Causal balance swizzle on blockIdx.x. Padded LDS stride 72 (2-way bank aliasing = free).
__global__ __launch_bounds__(256)
void attn_k(const bf16* __restrict__ Qp, const bf16* __restrict__ Kp,
            const bf16* __restrict__ Vtp, bf16* __restrict__ Obuf) {
  __shared__ __align__(16) bf16 shK[64 * 72];      // K[key][d]
  __shared__ __align__(16) bf16 shV[64 * 72];      // V[d][key]
  __shared__ __align__(16) bf16 shP[4][16 * 72];   // per-wave P round-trip
  const int tid  = threadIdx.x;
  const int wave = tid >> 6, lane = tid & 63;
  const int quad = lane >> 4, l16 = lane & 15;
  const int bh = blockIdx.y;
  const int bx = blockIdx.x;
  // balance swizzle: pair short and long causal blocks
  const int qb = (bx & 1) ? (31 - (bx >> 1)) : (bx >> 1);
  const int q0 = qb * 64 + wave * 16;

  const bf16* Qbh = Qp  + (size_t)bh * SEQ * 64;
  const bf16* Kbh = Kp  + (size_t)bh * SEQ * 64;
  const bf16* Vbh = Vtp + (size_t)bh * 64 * SEQ;   // (d, t)

  // A-operand layout: A[m=lane&15][k=quad*8+j]   [verified m120]
  bf16x8 aQ0 = ld8(&Qbh[(size_t)(q0 + l16) * 64 + quad * 8]);
  bf16x8 aQ1 = ld8(&Qbh[(size_t)(q0 + l16) * 64 + 32 + quad * 8]);

  f32x4 o[4];
  #pragma unroll
  for (int j = 0; j < 4; j++) o[j] = (f32x4){0.f, 0.f, 0.f, 0.f};
  float mrow[4], lrow[4];
  #pragma unroll
  for (int r = 0; r < 4; r++) { mrow[r] = NEG_SENT; lrow[r] = 0.f; }

  const float SC = 0.125f * LOG2E;
  const int LT = qb;              // last 64-key tile index for this block
  bf16* P = shP[wave];

  for (int kt = 0; kt <= LT; kt++) {
    const int kbase = kt * 64;
    // ---- stage K (64x64) and V (64x64) into LDS, all 256 threads ----
    #pragma unroll
    for (int s = 0; s < 2; s++) {
      int id  = tid + s * 256;          // 0..511
      int row = id >> 3;                // 0..63
      int c8  = (id & 7) * 8;           // 0..56
      *(uint4*)&shK[row * 72 + c8] =
          *(const uint4*)&Kbh[(size_t)(kbase + row) * 64 + c8];
      *(uint4*)&shV[row * 72 + c8] =
          *(const uint4*)&Vbh[(size_t)row * SEQ + kbase + c8];
    }
    __syncthreads();

    // ---- QK^T: 4 col-groups x 2 k-parts ----
    f32x4 s4[4];
    #pragma unroll
    for (int c = 0; c < 4; c++) s4[c] = (f32x4){0.f, 0.f, 0.f, 0.f};
    #pragma unroll
    for (int c = 0; c < 4; c++) {
      bf16x8 k0 = ld8(&shK[(c * 16 + l16) * 72 + quad * 8]);
      bf16x8 k1 = ld8(&shK[(c * 16 + l16) * 72 + 32 + quad * 8]);
      s4[c] = __builtin_amdgcn_mfma_f32_16x16x32_bf16(aQ0, k0, s4[c], 0, 0, 0);
      s4[c] = __builtin_amdgcn_mfma_f32_16x16x32_bf16(aQ1, k1, s4[c], 0, 0, 0);
    }
    // scale + causal mask (only the last tile straddles the diagonal)
    #pragma unroll
    for (int c = 0; c < 4; c++)
      #pragma unroll
      for (int r = 0; r < 4; r++) {
        float v = s4[c][r] * SC;
        if (kt == LT) {
          int key = kbase + c * 16 + l16;
          int row = q0 + quad * 4 + r;
          if (key > row) v = NEG_SENT;
        }
        s4[c][r] = v;
      }
    // ---- online softmax; a row's cols live in lanes quad*16+0..15 ----
    #pragma unroll
    for (int r = 0; r < 4; r++) {
      float mx = fmaxf(fmaxf(s4[0][r], s4[1][r]), fmaxf(s4[2][r], s4[3][r]));
      #pragma unroll
      for (int off = 1; off < 16; off <<= 1)
        mx = fmaxf(mx, __shfl_xor(mx, off, 64));
      float mn = fmaxf(mrow[r], mx);
      float alpha = exp2f(mrow[r] - mn);
      float p0 = exp2f(s4[0][r] - mn);
      float p1 = exp2f(s4[1][r] - mn);
      float p2 = exp2f(s4[2][r] - mn);
      float p3 = exp2f(s4[3][r] - mn);
      s4[0][r] = p0; s4[1][r] = p1; s4[2][r] = p2; s4[3][r] = p3;
      float rs = (p0 + p1) + (p2 + p3);
      #pragma unroll
      for (int off = 1; off < 16; off <<= 1)
        rs += __shfl_xor(rs, off, 64);
      lrow[r] = lrow[r] * alpha + rs;
      mrow[r] = mn;
      #pragma unroll
      for (int j = 0; j < 4; j++) o[j][r] *= alpha;
    }
    // ---- P: C-layout -> per-wave LDS -> A-layout ----
    #pragma unroll
    for (int c = 0; c < 4; c++)
      #pragma unroll
      for (int r = 0; r < 4; r++)
        P[(quad * 4 + r) * 72 + c * 16 + l16] = (bf16)s4[c][r];
    asm volatile("s_waitcnt lgkmcnt(0)" ::: "memory");
    bf16x8 aP0 = ld8(&P[l16 * 72 + quad * 8]);
    bf16x8 aP1 = ld8(&P[l16 * 72 + 32 + quad * 8]);
    // ---- PV: 4 d-groups x 2 k-parts ----
    #pragma unroll
    for (int j = 0; j < 4; j++) {
      bf16x8 v0 = ld8(&shV[(j * 16 + l16) * 72 + quad * 8]);
      bf16x8 v1 = ld8(&shV[(j * 16 + l16) * 72 + 32 + quad * 8]);
      o[j] = __builtin_amdgcn_mfma_f32_16x16x32_bf16(aP0, v0, o[j], 0, 0, 0);
      o[j] = __builtin_amdgcn_mfma_f32_16x16x32_bf16(aP1, v1, o[j], 0, 0, 0);
    }
    __syncthreads();
  }

  // finalize: divide by l, store to (b, t, h*64+d)
  const int b = bh >> 4, h = bh & 15;
  #pragma unroll
  for (int r = 0; r < 4; r++) {
    float inv = 1.0f / lrow[r];
    int t = q0 + quad * 4 + r;
    size_t rowo = ((size_t)(b * SEQ + t)) * D_MODEL + h * 64;
    #pragma unroll
    for (int j = 0; j < 4; j++)
      Obuf[rowo + j * 16 + l16] = (bf16)(o[j][r] * inv);
  }
}

extern "C" void kernel_launch(void* const* d_in, const int* in_sizes, int n_in,
                              void* d_out, int out_size, void* d_ws, size_t ws_size,
                              hipStream_t stream) {
  const float* x    = (const float*)d_in[0];   // (2,2048,1024) fp32
  const float* Wqkv = (const float*)d_in[1];   // (1024,3072)  fp32
  const float* bqkv = (const float*)d_in[2];   // (3072,)      fp32
  const float* Wout = (const float*)d_in[3];   // (1024,1024)  fp32
  const float* bout = (const float*)d_in[4];   // (1024,)      fp32
  float* out = (float*)d_out;                  // (2,2048,1024) fp32

  char* ws = (char*)d_ws;
  bf16* x16    = (bf16*)(ws);                     //  8 MB; reused as Obuf after gemm0
  bf16* Wqkv_t = (bf16*)(ws + 8388608);           //  6 MB
  bf16* Wout_t = (bf16*)(ws + 14680064);          //  2 MB
  bf16* Qp     = (bf16*)(ws + 16777216);          //  8 MB
  bf16* Kp     = (bf16*)(ws + 25165824);          //  8 MB
  bf16* Vtp    = (bf16*)(ws + 33554432);          //  8 MB  -> total 40 MB
  bf16* Obuf   = x16;

  cvt_f32_bf16<<<(4096 * 1024 / 4 + 255) / 256, 256, 0, stream>>>(x, x16, 4096 * 1024);
  transpose_cvt<<<dim3(3072 / 32, 1024 / 32), dim3(32, 8), 0, stream>>>(Wqkv, Wqkv_t, 1024, 3072);
  transpose_cvt<<<dim3(1024 / 32, 1024 / 32), dim3(32, 8), 0, stream>>>(Wout, Wout_t, 1024, 1024);

  gemm_bt<<<dim3(3072 / 128, 4096 / 128), 256, 0, stream>>>(
      x16, Wqkv_t, bqkv, nullptr, Qp, Kp, Vtp, 3072, 0);

  attn_k<<<dim3(SEQ / 64, BATCH * N_HEADS), 256, 0, stream>>>(Qp, Kp, Vtp, Obuf);

  gemm_bt<<<dim3(1024 / 128, 4096 / 128), 256, 0, stream>>>(
      Obuf, Wout_t, bout, out, nullptr, nullptr, nullptr, 1024, 1);
}

// Round 5
// 302.348 us; speedup vs baseline: 1.3622x; 1.0704x over previous
//
#include <hip/hip_runtime.h>
#include <hip/hip_bf16.h>
#include <stdint.h>

typedef __bf16 bf16;
typedef __bf16 bf16x8 __attribute__((ext_vector_type(8)));
typedef float  f32x4  __attribute__((ext_vector_type(4)));

#define D_MODEL 1024
#define N_HEADS 16
#define HEAD_DIM 64
#define SEQ 2048
#define BATCH 2
#define LOG2E 1.4426950408889634f
#define NEG_SENT -3.0e4f   // finite "-inf": exp2f(NEG_SENT - mn) == 0; never NaNs

__device__ __forceinline__ bf16x8 ld8(const bf16* p) { return *(const bf16x8*)p; }

// ---------------- fp32 -> bf16 elementwise convert ----------------
__global__ void cvt_f32_bf16(const float* __restrict__ in, bf16* __restrict__ out, int n) {
  int i = (blockIdx.x * blockDim.x + threadIdx.x) * 4;
  if (i < n) {
    float4 v = *(const float4*)&in[i];
    bf16 o[4] = {(bf16)v.x, (bf16)v.y, (bf16)v.z, (bf16)v.w};
    *(uint2*)&out[i] = *(uint2*)o;
  }
}

// ---------------- weight transpose+convert: fp32 (R x C) -> bf16 (C x R) ----------------
__global__ void transpose_cvt(const float* __restrict__ in, bf16* __restrict__ out,
                              int R, int C) {
  __shared__ float tile[32][33];
  int c0 = blockIdx.x * 32, r0 = blockIdx.y * 32;
  int tx = threadIdx.x;
  for (int i = threadIdx.y; i < 32; i += 8)
    tile[i][tx] = in[(size_t)(r0 + i) * C + c0 + tx];
  __syncthreads();
  for (int i = threadIdx.y; i < 32; i += 8)
    out[(size_t)(c0 + i) * R + r0 + tx] = (bf16)tile[tx][i];
}

// ---------------- GEMM: C[M x N] = A[M x 1024] * Bt[N x 1024]^T + bias ----------------
__global__ __launch_bounds__(256)
void gemm_bt(const bf16* __restrict__ A, const bf16* __restrict__ Bt,
             const float* __restrict__ bias, float* __restrict__ outf,
             bf16* __restrict__ Qp, bf16* __restrict__ Kp, bf16* __restrict__ Vtp,
             int N, int mode) {
  __shared__ __align__(16) bf16 shA[128 * 40];
  __shared__ __align__(16) bf16 shB[128 * 40];
  const int tid  = threadIdx.x;
  const int bm0  = blockIdx.y * 128, bn0 = blockIdx.x * 128;
  const int wave = tid >> 6, lane = tid & 63;
  const int quad = lane >> 4, l16 = lane & 15;
  const int wm = (wave >> 1) * 64, wn = (wave & 1) * 64;

  f32x4 acc[4][4];
  #pragma unroll
  for (int i = 0; i < 4; i++)
    #pragma unroll
    for (int j = 0; j < 4; j++)
      acc[i][j] = (f32x4){0.f, 0.f, 0.f, 0.f};

  for (int k0 = 0; k0 < 1024; k0 += 32) {
    #pragma unroll
    for (int s = 0; s < 2; s++) {
      int c = tid + s * 256;
      int row = c >> 2;
      int kc  = (c & 3) << 3;
      *(uint4*)&shA[row * 40 + kc] =
          *(const uint4*)&A[(size_t)(bm0 + row) * 1024 + k0 + kc];
      *(uint4*)&shB[row * 40 + kc] =
          *(const uint4*)&Bt[(size_t)(bn0 + row) * 1024 + k0 + kc];
    }
    __syncthreads();
    bf16x8 af[4], bg[4];
    #pragma unroll
    for (int i = 0; i < 4; i++)
      af[i] = ld8(&shA[(wm + i * 16 + l16) * 40 + quad * 8]);
    #pragma unroll
    for (int j = 0; j < 4; j++)
      bg[j] = ld8(&shB[(wn + j * 16 + l16) * 40 + quad * 8]);
    #pragma unroll
    for (int i = 0; i < 4; i++)
      #pragma unroll
      for (int j = 0; j < 4; j++)
        acc[i][j] = __builtin_amdgcn_mfma_f32_16x16x32_bf16(af[i], bg[j], acc[i][j], 0, 0, 0);
    __syncthreads();
  }

  // epilogue; C/D layout: col = lane&15, row = quad*4 + reg   [verified m89/m91]
  #pragma unroll
  for (int i = 0; i < 4; i++) {
    #pragma unroll
    for (int j = 0; j < 4; j++) {
      int gn = bn0 + wn + j * 16 + l16;
      float bv = bias[gn];
      #pragma unroll
      for (int r = 0; r < 4; r++) {
        int gm = bm0 + wm + i * 16 + quad * 4 + r;
        float v = acc[i][j][r] + bv;
        if (mode == 1) {
          outf[(size_t)gm * N + gn] = v;
        } else {
          int which = gn >> 10, rem = gn & 1023;
          int h = rem >> 6, d = rem & 63;
          int b = gm >> 11, t = gm & 2047;
          int bh = b * N_HEADS + h;
          if (which == 0)      Qp[((size_t)bh * SEQ + t) * 64 + d]  = (bf16)v;
          else if (which == 1) Kp[((size_t)bh * SEQ + t) * 64 + d]  = (bf16)v;
          else                 Vtp[((size_t)bh * 64 + d) * SEQ + t] = (bf16)v;
        }
      }
    }
  }
}

// ---------------- flash attention (causal) v3 ----------------
// Block = 4 waves; wave = 32 q rows -> 128 q rows per block. 64-key LDS tiles
// shared by all waves. Max-reduce chains interleaved; row-sum via ones-MFMA.
__global__ __launch_bounds__(256)
void attn_k(const bf16* __restrict__ Qp, const bf16* __restrict__ Kp,
            const bf16* __restrict__ Vtp, bf16* __restrict__ Obuf) {
  __shared__ __align__(16) bf16 shK[64 * 72];      // K[key][d]
  __shared__ __align__(16) bf16 shV[64 * 72];      // V[d][key]
  __shared__ __align__(16) bf16 shP[4][32 * 72];   // per-wave P round-trip (32 rows)
  const int tid  = threadIdx.x;
  const int wave = tid >> 6, lane = tid & 63;
  const int quad = lane >> 4, l16 = lane & 15;
  const int bh = blockIdx.y;
  const int bx = blockIdx.x;
  // balance swizzle: pair short and long causal blocks (sum of pair = const)
  const int qb = (bx & 1) ? (15 - (bx >> 1)) : (bx >> 1);
  const int qw0 = qb * 128 + wave * 32;            // this wave's first q row

  const bf16* Qbh = Qp  + (size_t)bh * SEQ * 64;
  const bf16* Kbh = Kp  + (size_t)bh * SEQ * 64;
  const bf16* Vbh = Vtp + (size_t)bh * 64 * SEQ;   // (d, t)

  // A-operand layout: A[m=lane&15][k=quad*8+j]   [verified m120]
  bf16x8 aQ[2][2];
  #pragma unroll
  for (int mA = 0; mA < 2; mA++)
    #pragma unroll
    for (int p = 0; p < 2; p++)
      aQ[mA][p] = ld8(&Qbh[(size_t)(qw0 + mA * 16 + l16) * 64 + p * 32 + quad * 8]);

  f32x4 o[2][4];
  float mrow[2][4], lrow[2][4];
  #pragma unroll
  for (int mA = 0; mA < 2; mA++)
    #pragma unroll
    for (int j = 0; j < 4; j++) {
      o[mA][j] = (f32x4){0.f, 0.f, 0.f, 0.f};
      mrow[mA][j] = NEG_SENT; lrow[mA][j] = 0.f;
    }

  const float SC = 0.125f * LOG2E;
  const int LT = 2 * qb + 1;            // last 64-key tile for this block
  bf16* P = shP[wave];
  const bf16 one_bf = (bf16)1.0f;
  bf16x8 ones = {one_bf, one_bf, one_bf, one_bf, one_bf, one_bf, one_bf, one_bf};

  for (int kt = 0; kt <= LT; kt++) {
    const int kbase = kt * 64;
    __syncthreads();                    // protect shK/shV from previous tile's readers
    // ---- stage K (64x64) and V (64x64) into LDS, all 256 threads ----
    #pragma unroll
    for (int s = 0; s < 2; s++) {
      int id  = tid + s * 256;          // 0..511
      int row = id >> 3;                // 0..63
      int c8  = (id & 7) * 8;           // 0..56
      *(uint4*)&shK[row * 72 + c8] =
          *(const uint4*)&Kbh[(size_t)(kbase + row) * 64 + c8];
      *(uint4*)&shV[row * 72 + c8] =
          *(const uint4*)&Vbh[(size_t)row * SEQ + kbase + c8];
    }
    __syncthreads();

    if (kbase > qw0 + 31) continue;     // wave-uniform: tile fully above diagonal

    // ---- QK^T: K-frags read once, used by both m-halves ----
    bf16x8 kf[2][4];
    #pragma unroll
    for (int c = 0; c < 4; c++) {
      kf[0][c] = ld8(&shK[(c * 16 + l16) * 72 + quad * 8]);
      kf[1][c] = ld8(&shK[(c * 16 + l16) * 72 + 32 + quad * 8]);
    }
    f32x4 s4[2][4];
    #pragma unroll
    for (int mA = 0; mA < 2; mA++)
      #pragma unroll
      for (int c = 0; c < 4; c++) {
        f32x4 acc = (f32x4){0.f, 0.f, 0.f, 0.f};
        acc = __builtin_amdgcn_mfma_f32_16x16x32_bf16(aQ[mA][0], kf[0][c], acc, 0, 0, 0);
        acc = __builtin_amdgcn_mfma_f32_16x16x32_bf16(aQ[mA][1], kf[1][c], acc, 0, 0, 0);
        s4[mA][c] = acc;
      }

    // scale + causal mask
    const bool needMask = (kbase + 63) > qw0;
    #pragma unroll
    for (int mA = 0; mA < 2; mA++)
      #pragma unroll
      for (int c = 0; c < 4; c++)
        #pragma unroll
        for (int r = 0; r < 4; r++) {
          float v = s4[mA][c][r] * SC;
          if (needMask) {
            int key = kbase + c * 16 + l16;
            int row = qw0 + mA * 16 + quad * 4 + r;
            if (key > row) v = NEG_SENT;
          }
          s4[mA][c][r] = v;
        }

    // ---- online softmax: interleaved max butterflies (8 independent chains) ----
    float mx[2][4];
    #pragma unroll
    for (int mA = 0; mA < 2; mA++)
      #pragma unroll
      for (int r = 0; r < 4; r++)
        mx[mA][r] = fmaxf(fmaxf(s4[mA][0][r], s4[mA][1][r]),
                          fmaxf(s4[mA][2][r], s4[mA][3][r]));
    #pragma unroll
    for (int off = 1; off < 16; off <<= 1)
      #pragma unroll
      for (int mA = 0; mA < 2; mA++)
        #pragma unroll
        for (int r = 0; r < 4; r++)
          mx[mA][r] = fmaxf(mx[mA][r], __shfl_xor(mx[mA][r], off, 64));

    #pragma unroll
    for (int mA = 0; mA < 2; mA++)
      #pragma unroll
      for (int r = 0; r < 4; r++) {
        float mn = fmaxf(mrow[mA][r], mx[mA][r]);
        float alpha = exp2f(mrow[mA][r] - mn);
        mrow[mA][r] = mn;
        lrow[mA][r] *= alpha;
        #pragma unroll
        for (int j = 0; j < 4; j++) o[mA][j][r] *= alpha;
        #pragma unroll
        for (int c = 0; c < 4; c++)
          s4[mA][c][r] = exp2f(s4[mA][c][r] - mn);
      }

    // ---- P: C-layout -> per-wave LDS -> A-layout ----
    #pragma unroll
    for (int mA = 0; mA < 2; mA++)
      #pragma unroll
      for (int c = 0; c < 4; c++)
        #pragma unroll
        for (int r = 0; r < 4; r++)
          P[(mA * 16 + quad * 4 + r) * 72 + c * 16 + l16] = (bf16)s4[mA][c][r];
    asm volatile("s_waitcnt lgkmcnt(0)" ::: "memory");

    bf16x8 vf[2][4];
    #pragma unroll
    for (int j = 0; j < 4; j++) {
      vf[0][j] = ld8(&shV[(j * 16 + l16) * 72 + quad * 8]);
      vf[1][j] = ld8(&shV[(j * 16 + l16) * 72 + 32 + quad * 8]);
    }
    #pragma unroll
    for (int mA = 0; mA < 2; mA++) {
      bf16x8 aP0 = ld8(&P[(mA * 16 + l16) * 72 + quad * 8]);
      bf16x8 aP1 = ld8(&P[(mA * 16 + l16) * 72 + 32 + quad * 8]);
      // row-sum of P via ones-MFMA: C[r] = sum_k P[row,k] (same reg<->row map as lrow)
      f32x4 rs = (f32x4){0.f, 0.f, 0.f, 0.f};
      rs = __builtin_amdgcn_mfma_f32_16x16x32_bf16(aP0, ones, rs, 0, 0, 0);
      rs = __builtin_amdgcn_mfma_f32_16x16x32_bf16(aP1, ones, rs, 0, 0, 0);
      #pragma unroll
      for (int j = 0; j < 4; j++) {
        o[mA][j] = __builtin_amdgcn_mfma_f32_16x16x32_bf16(aP0, vf[0][j], o[mA][j], 0, 0, 0);
        o[mA][j] = __builtin_amdgcn_mfma_f32_16x16x32_bf16(aP1, vf[1][j], o[mA][j], 0, 0, 0);
      }
      #pragma unroll
      for (int r = 0; r < 4; r++) lrow[mA][r] += rs[r];
    }
  }

  // finalize: divide by l, store to (b, t, h*64+d)
  const int b = bh >> 4, h = bh & 15;
  #pragma unroll
  for (int mA = 0; mA < 2; mA++)
    #pragma unroll
    for (int r = 0; r < 4; r++) {
      float inv = 1.0f / lrow[mA][r];
      int t = qw0 + mA * 16 + quad * 4 + r;
      size_t rowo = ((size_t)(b * SEQ + t)) * D_MODEL + h * 64;
      #pragma unroll
      for (int j = 0; j < 4; j++)
        Obuf[rowo + j * 16 + l16] = (bf16)(o[mA][j][r] * inv);
    }
}

extern "C" void kernel_launch(void* const* d_in, const int* in_sizes, int n_in,
                              void* d_out, int out_size, void* d_ws, size_t ws_size,
                              hipStream_t stream) {
  const float* x    = (const float*)d_in[0];   // (2,2048,1024) fp32
  const float* Wqkv = (const float*)d_in[1];   // (1024,3072)  fp32
  const float* bqkv = (const float*)d_in[2];   // (3072,)      fp32
  const float* Wout = (const float*)d_in[3];   // (1024,1024)  fp32
  const float* bout = (const float*)d_in[4];   // (1024,)      fp32
  float* out = (float*)d_out;                  // (2,2048,1024) fp32

  char* ws = (char*)d_ws;
  bf16* x16    = (bf16*)(ws);                     //  8 MB; reused as Obuf after gemm0
  bf16* Wqkv_t = (bf16*)(ws + 8388608);           //  6 MB
  bf16* Wout_t = (bf16*)(ws + 14680064);          //  2 MB
  bf16* Qp     = (bf16*)(ws + 16777216);          //  8 MB
  bf16* Kp     = (bf16*)(ws + 25165824);          //  8 MB
  bf16* Vtp    = (bf16*)(ws + 33554432);          //  8 MB  -> total 40 MB
  bf16* Obuf   = x16;

  cvt_f32_bf16<<<(4096 * 1024 / 4 + 255) / 256, 256, 0, stream>>>(x, x16, 4096 * 1024);
  transpose_cvt<<<dim3(3072 / 32, 1024 / 32), dim3(32, 8), 0, stream>>>(Wqkv, Wqkv_t, 1024, 3072);
  transpose_cvt<<<dim3(1024 / 32, 1024 / 32), dim3(32, 8), 0, stream>>>(Wout, Wout_t, 1024, 1024);

  gemm_bt<<<dim3(3072 / 128, 4096 / 128), 256, 0, stream>>>(
      x16, Wqkv_t, bqkv, nullptr, Qp, Kp, Vtp, 3072, 0);

  attn_k<<<dim3(SEQ / 128, BATCH * N_HEADS), 256, 0, stream>>>(Qp, Kp, Vtp, Obuf);

  gemm_bt<<<dim3(1024 / 128, 4096 / 128), 256, 0, stream>>>(
      Obuf, Wout_t, bout, out, nullptr, nullptr, nullptr, 1024, 1);
}